// Round 9
// baseline (90.869 us; speedup 1.0000x reference)
//
#include <hip/hip_runtime.h>
#include <math.h>

#define Hd 264
#define Wd 480
#define HW (Hd * Wd)
#define NB 16
#define NC 9
#define KK 50
#define NPLANE (NB * NC)
#define NDET (NB * KK)
#define CAP 6912
#define RPC 22                 // rows per chunk
#define NCH (Hd / RPC)         // 12
#define SLAB_CAP 1024
#define SCAP 1024
#define PI_F 3.14159274101257324f
#define TWO_PI_F 6.28318548202514648f

__device__ const float DIMM[9][3] = {
    {3.99331126f, 1.54370861f, 1.64175497f},
    {0.295f, 1.6f, 0.3175f},
    {1.34645161f, 1.55322581f, 0.3883871f},
    {2.503f, 1.72f, 1.077f},
    {9.1775f, 2.95f, 2.3425f},
    {10.3655102f, 3.31632653f, 2.45469388f},
    {6.016911083f, 3.412001685f, 2.2783185f},
    {4.824963f, 2.046904f, 1.78939f},
    {8.8040879f, 2.916193f, 2.07649252f}};

__device__ const float ACENT[4] = {0.0f, 1.57079637050628662f, 3.14159274101257324f, -1.57079637050628662f};

__device__ __forceinline__ float4 max4(float4 a, float4 b) {
    return make_float4(fmaxf(a.x, b.x), fmaxf(a.y, b.y), fmaxf(a.z, b.z), fmaxf(a.w, b.w));
}

// Kernel 1: barrier-free wave-wide 5x5 NMS. One wave per block; lane owns 8
// pixels (2 float4). Vertical 5-tap in a register ring; horizontal neighbor
// halo via __shfl (no LDS row, no barriers -> loads stay pipelined). Survivors
// appended to per-(plane,chunk) slab + exact count. Key = (value_bits<<32)|~idx.
__global__ __launch_bounds__(64) void nms_wave(const float* __restrict__ cls,
                                               unsigned long long* __restrict__ slabs,
                                               int* __restrict__ slabCnt,
                                               int* __restrict__ batchCnt) {
    __shared__ unsigned long long sbuf[SLAB_CAP];
    __shared__ int scnt;

    const int plane = blockIdx.y;
    const int chunk = blockIdx.x;
    const int lane = threadIdx.x;
    const bool act = lane < 60;                  // 60 lanes x 8 px = 480
    const float* hp = cls + (size_t)plane * HW;
    const int gy0 = chunk * RPC;

    if (lane == 0) {
        scnt = 0;
        if (chunk == 0 && plane < NB) batchCnt[plane] = 0;  // fan-in counters (stream-ordered)
    }

    const float4 NEG = make_float4(-INFINITY, -INFINITY, -INFINITY, -INFINITY);
    float4 a0 = NEG, b0 = NEG, a1 = NEG, b1 = NEG, a2 = NEG, b2 = NEG,
           a3 = NEG, b3 = NEG, a4 = NEG, b4 = NEG;

    // depth-2 row prefetch
    float4 na0 = NEG, nb0 = NEG, na1 = NEG, nb1 = NEG;
    {
        int ry = gy0 - 2;
        if (act && ry >= 0) {
            const float4* rp = (const float4*)(hp + (size_t)ry * Wd) + lane * 2;
            na0 = rp[0]; nb0 = rp[1];
        }
        ry = gy0 - 1;
        if (act && ry >= 0) {
            const float4* rp = (const float4*)(hp + (size_t)ry * Wd) + lane * 2;
            na1 = rp[0]; nb1 = rp[1];
        }
    }

    for (int t = 0; t < RPC + 4; ++t) {
        const float4 ca = na0, cb = nb0;
        na0 = na1; nb0 = nb1;
        const int ry = gy0 + t;                  // row for 2-ahead prefetch
        if (t < RPC + 2) {
            if (act && ry < Hd) {
                const float4* rp = (const float4*)(hp + (size_t)ry * Wd) + lane * 2;
                na1 = rp[0]; nb1 = rp[1];
            } else {
                na1 = NEG; nb1 = NEG;
            }
        }
        // ring shift
        a0 = a1; b0 = b1; a1 = a2; b1 = b2; a2 = a3; b2 = b3; a3 = a4; b3 = b4;
        a4 = ca; b4 = cb;
        if (t < 4) continue;

        // vertical 5-tap
        const float4 vA = max4(max4(a0, a1), max4(max4(a2, a3), a4));
        const float4 vB = max4(max4(b0, b1), max4(max4(b2, b3), b4));

        // horizontal halo via shfl (lanes >=60 hold -inf -> right edge safe)
        float lm2 = __shfl_up(vB.z, 1);
        float lm1 = __shfl_up(vB.w, 1);
        const float r8 = __shfl_down(vA.x, 1);
        const float r9 = __shfl_down(vA.y, 1);
        if (lane == 0) { lm2 = -INFINITY; lm1 = -INFINITY; }

        // pairwise maxes p_i = max(v[i],v[i+1]); hm_i = max(p_{i-2}, v[i], p_{i+1})
        const float pm2 = fmaxf(lm2, lm1);
        const float pm1 = fmaxf(lm1, vA.x);
        const float p0 = fmaxf(vA.x, vA.y);
        const float p1 = fmaxf(vA.y, vA.z);
        const float p2 = fmaxf(vA.z, vA.w);
        const float p3 = fmaxf(vA.w, vB.x);
        const float p4 = fmaxf(vB.x, vB.y);
        const float p5 = fmaxf(vB.y, vB.z);
        const float p6 = fmaxf(vB.z, vB.w);
        const float p7 = fmaxf(vB.w, r8);
        const float p8 = fmaxf(r8, r9);

        const float hm0 = fmaxf(pm2, fmaxf(vA.x, p1));
        const float hm1 = fmaxf(pm1, fmaxf(vA.y, p2));
        const float hm2 = fmaxf(p0, fmaxf(vA.z, p3));
        const float hm3 = fmaxf(p1, fmaxf(vA.w, p4));
        const float hm4 = fmaxf(p2, fmaxf(vB.x, p5));
        const float hm5 = fmaxf(p3, fmaxf(vB.y, p6));
        const float hm6 = fmaxf(p4, fmaxf(vB.z, p7));
        const float hm7 = fmaxf(p5, fmaxf(vB.w, p8));

        if (act) {
            const int gy = gy0 + t - 4;
            const unsigned int base = (unsigned int)(gy * Wd + lane * 8);
#define APPEND(val, off)                                                                     \
            {                                                                                \
                const int p_ = atomicAdd(&scnt, 1);                                          \
                if (p_ < SLAB_CAP)                                                           \
                    sbuf[p_] = ((unsigned long long)__float_as_uint(val) << 32) |            \
                               (unsigned long long)(0xFFFFFFFFu - (base + (off)));           \
            }
            if (a2.x == hm0) APPEND(a2.x, 0)
            if (a2.y == hm1) APPEND(a2.y, 1)
            if (a2.z == hm2) APPEND(a2.z, 2)
            if (a2.w == hm3) APPEND(a2.w, 3)
            if (b2.x == hm4) APPEND(b2.x, 4)
            if (b2.y == hm5) APPEND(b2.y, 5)
            if (b2.z == hm6) APPEND(b2.z, 6)
            if (b2.w == hm7) APPEND(b2.w, 7)
#undef APPEND
        }
    }

    const int n = min(scnt, SLAB_CAP);
    const int slab = plane * NCH + chunk;
    unsigned long long* dst = slabs + (size_t)slab * SLAB_CAP;
    for (int j = lane; j < n; j += 64) dst[j] = sbuf[j];
    if (lane == 0) slabCnt[slab] = n;
}

// Kernel 2: per-plane exact top-50 (fast threshold path / radix fallback),
// then device-scope fan-in: the 9th finishing block of each batch inline-ranks
// the batch's 450 keys and writes dScore/dInd/dCls.
__global__ __launch_bounds__(256) void plane_topk(const unsigned long long* __restrict__ slabs,
                                                  const int* __restrict__ slabCnt,
                                                  unsigned long long* __restrict__ planeKeys,
                                                  int* __restrict__ batchCnt,
                                                  float* __restrict__ dScore,
                                                  int* __restrict__ dInd,
                                                  int* __restrict__ dCls) {
    __shared__ unsigned long long cand[CAP];
    __shared__ int hist[4096];
    __shared__ int csum[256];
    __shared__ unsigned long long S[SCAP];
    __shared__ int soff[NCH + 1];
    __shared__ int s_b1, s_acc, s_b2, s_scnt, s_need2, s_nhi, s_last;
    __shared__ unsigned long long wmax[4];
    __shared__ unsigned long long sprev;

    const int plane = blockIdx.x;
    const int tid = threadIdx.x;

    if (tid < NCH) soff[tid + 1] = min(slabCnt[plane * NCH + tid], SLAB_CAP);
    if (tid == 0) { soff[0] = 0; s_scnt = 0; s_nhi = 0; }
    for (int j = tid; j < 4096; j += 256) hist[j] = 0;
    __syncthreads();
    if (tid == 0) {
        for (int c = 1; c <= NCH; ++c) soff[c] += soff[c - 1];
    }
    __syncthreads();
    const int n = min(soff[NCH], CAP);

    for (int j = tid; j < n; j += 256) {
        int lo = 0, hi = NCH;
        while (hi - lo > 1) { const int mid = (lo + hi) >> 1; if (soff[mid] <= j) lo = mid; else hi = mid; }
        cand[j] = slabs[(size_t)(plane * NCH + lo) * SLAB_CAP + (j - soff[lo])];
    }
    __syncthreads();

    // ---- Fast path: fixed value threshold 0.998 ----
    const unsigned int TB = __float_as_uint(0.998f);
    {
        int myhi = 0;
        for (int j = tid; j < n; j += 256) myhi += ((unsigned int)(cand[j] >> 32) >= TB) ? 1 : 0;
#pragma unroll
        for (int s = 32; s > 0; s >>= 1) myhi += __shfl_down(myhi, s);
        if ((tid & 63) == 0) atomicAdd(&s_nhi, myhi);
    }
    __syncthreads();
    const int nHi = s_nhi;

    if (nHi >= KK && nHi <= SCAP) {
        for (int j = tid; j < n; j += 256) {
            const unsigned long long k = cand[j];
            if ((unsigned int)(k >> 32) >= TB) {
                const int p = atomicAdd(&s_scnt, 1);
                S[p] = k;
            }
        }
        __syncthreads();
        const int sc = s_scnt;
        for (int idx = tid; idx < sc; idx += 256) {
            const unsigned long long k = S[idx];
            int r = 0;
            for (int j = 0; j < sc; ++j) r += (S[j] > k) ? 1 : 0;
            if (r < KK) planeKeys[plane * KK + r] = k;
        }
    } else {
        // ---- Fallback: two-level radix histogram (any-data correctness) ----
        for (int j = tid; j < n; j += 256) atomicAdd(&hist[(unsigned int)(cand[j] >> 52)], 1);
        __syncthreads();
        {
            int s = 0;
#pragma unroll 4
            for (int q = 0; q < 16; ++q) s += hist[tid * 16 + q];
            csum[tid] = s;
        }
        __syncthreads();
        if (tid == 0) {
            int acc = 0, b1 = 0;
            int t = 255;
            for (; t >= 0; --t) { if (acc + csum[t] >= KK) break; acc += csum[t]; }
            if (t < 0) { b1 = 0; } else {
                int b = t * 16 + 15;
                for (; b > t * 16; --b) { if (acc + hist[b] >= KK) break; acc += hist[b]; }
                b1 = b;
            }
            s_b1 = b1;
            s_acc = acc;
            s_need2 = (acc + hist[b1] > SCAP) ? 1 : 0;
        }
        __syncthreads();
        const int b1 = s_b1;
        const int need2 = s_need2;
        int b2 = 0;

        if (need2) {
            for (int j = tid; j < 4096; j += 256) hist[j] = 0;
            __syncthreads();
            for (int j = tid; j < n; j += 256) {
                const unsigned long long k = cand[j];
                if ((unsigned int)(k >> 52) == (unsigned int)b1)
                    atomicAdd(&hist[(unsigned int)(k >> 40) & 0xFFFu], 1);
            }
            __syncthreads();
            {
                int s = 0;
#pragma unroll 4
                for (int q = 0; q < 16; ++q) s += hist[tid * 16 + q];
                csum[tid] = s;
            }
            __syncthreads();
            if (tid == 0) {
                const int target = KK - s_acc;
                int acc2 = 0, bb = 0;
                int t = 255;
                for (; t >= 0; --t) { if (acc2 + csum[t] >= target) break; acc2 += csum[t]; }
                if (t < 0) { bb = 0; } else {
                    int b = t * 16 + 15;
                    for (; b > t * 16; --b) { if (acc2 + hist[b] >= target) break; acc2 += hist[b]; }
                    bb = b;
                }
                s_b2 = bb;
            }
            __syncthreads();
            b2 = s_b2;
        }

        for (int j = tid; j < n; j += 256) {
            const unsigned long long k = cand[j];
            const unsigned int p1 = (unsigned int)(k >> 52);
            bool sel;
            if (!need2) sel = (p1 >= (unsigned int)b1);
            else sel = (p1 > (unsigned int)b1) ||
                       (p1 == (unsigned int)b1 && ((unsigned int)(k >> 40) & 0xFFFu) >= (unsigned int)b2);
            if (sel) {
                const int p = atomicAdd(&s_scnt, 1);
                if (p < SCAP) S[p] = k;
            }
        }
        for (int j = tid; j < KK; j += 256) planeKeys[plane * KK + j] = 0;
        __syncthreads();
        const int scnt = s_scnt;

        if (scnt <= SCAP) {
            for (int idx = tid; idx < scnt; idx += 256) {
                const unsigned long long k = S[idx];
                int r = 0;
                for (int j = 0; j < scnt; ++j) r += (S[j] > k) ? 1 : 0;
                if (r < KK) planeKeys[plane * KK + r] = k;
            }
        } else {
            unsigned long long prev = ~0ull;
            for (int it = 0; it < KK; ++it) {
                unsigned long long mk = 0;
                for (int j = tid; j < n; j += 256) {
                    unsigned long long k = cand[j];
                    if (k == prev) { cand[j] = 0; k = 0; }
                    if (k > mk) mk = k;
                }
                for (int s = 32; s > 0; s >>= 1) {
                    const unsigned long long o = __shfl_down(mk, s);
                    if (o > mk) mk = o;
                }
                if ((tid & 63) == 0) wmax[tid >> 6] = mk;
                __syncthreads();
                if (tid == 0) {
                    unsigned long long m = wmax[0];
                    if (wmax[1] > m) m = wmax[1];
                    if (wmax[2] > m) m = wmax[2];
                    if (wmax[3] > m) m = wmax[3];
                    planeKeys[plane * KK + it] = m;
                    sprev = m;
                }
                __syncthreads();
                prev = sprev;
            }
        }
    }

    // ---- Fan-in: last block of each batch ranks the batch's 450 keys ----
    __threadfence();          // release this thread's planeKeys writes
    __syncthreads();
    if (tid == 0) s_last = (atomicAdd(&batchCnt[plane / NC], 1) == NC - 1) ? 1 : 0;
    __syncthreads();
    if (!s_last) return;
    __threadfence();          // acquire other blocks' planeKeys

    const int b = plane / NC;
    unsigned int* sidx = (unsigned int*)hist;  // reuse LDS
    for (int j = tid; j < NC * KK; j += 256) {
        const unsigned long long pk = planeKeys[(b * NC + j / KK) * KK + (j % KK)];
        sidx[j] = 0xFFFFFFFFu - (unsigned int)(pk & 0xFFFFFFFFull);
        S[j] = (pk & 0xFFFFFFFF00000000ull) | (unsigned long long)(0xFFFFFFFFu - (unsigned int)j);
    }
    __syncthreads();
    for (int idx = tid; idx < NC * KK; idx += 256) {
        const unsigned long long k = S[idx];
        int r = 0;
        for (int j = 0; j < NC * KK; ++j) r += (S[j] > k) ? 1 : 0;
        if (r < KK) {
            dScore[b * KK + r] = __uint_as_float((unsigned int)(k >> 32));
            dInd[b * KK + r] = (int)sidx[idx];
            dCls[b * KK + r] = idx / KK;
        }
    }
}

// Kernel 3 (R8 version): fused per-detection finalize, 800 blocks x 64.
__global__ __launch_bounds__(64) void finalize(const float* __restrict__ regs,
                                               const float* __restrict__ calib,
                                               const float* __restrict__ dScore,
                                               const int* __restrict__ dInd,
                                               const int* __restrict__ dCls,
                                               float* __restrict__ out) {
    __shared__ float s[26];
    const int i = blockIdx.x;
    const int lane = threadIdx.x;
    const int ind0 = dInd[i];
    const int ind = (ind0 >= 0 && ind0 < HW) ? ind0 : 0;
    const int b = i / KK;

    if (lane < 26) {
        const int ch = (lane < 6) ? lane : lane + 16;  // 0-5, 22-24, 25-40, 41
        s[lane] = regs[(size_t)b * 46 * HW + (size_t)ch * HW + (size_t)ind];
    }

    float m = -INFINITY;
    for (int j = lane; j < NDET; j += 64) {
        if (dInd[j] == ind0 && dScore[j] >= 0.29f) {
            m = fmaxf(m, (float)dCls[j] * 10000.0f - (float)j);
        }
    }
#pragma unroll
    for (int sft = 32; sft > 0; sft >>= 1) m = fmaxf(m, __shfl_down(m, sft));
    __syncthreads();
    if (lane != 0) return;

    const int cls = dCls[i];
    const float score = dScore[i];
    const bool th = score >= 0.29f;
    const float key_i = th ? (float)cls * 10000.0f - (float)i : -INFINITY;
    const bool valid = th && (key_i == m);

    const float x = (float)(ind % Wd);
    const float y = (float)(ind / Wd);

    const float r0 = fmaxf(s[0], 0.0f), r1 = fmaxf(s[1], 0.0f);
    const float r2 = fmaxf(s[2], 0.0f), r3 = fmaxf(s[3], 0.0f);
    const float cx = x + s[4];
    const float cy = y + s[5];

    const float bx1 = fminf(fmaxf((cx - r0) * 4.0f, 0.0f), 1920.0f);
    const float by1 = fminf(fmaxf((cy - r1) * 4.0f, 0.0f), 1056.0f);
    const float bx2 = fminf(fmaxf((cx + r2) * 4.0f, 0.0f), 1920.0f);
    const float by2 = fminf(fmaxf((cy + r3) * 4.0f, 0.0f), 1056.0f);

    const float dim0 = expf(s[6]) * DIMM[cls][0];
    const float dim1 = expf(s[7]) * DIMM[cls][1];
    const float dim2 = expf(s[8]) * DIMM[cls][2];

    const float sig = 1.0f / (1.0f + expf(-s[25]));
    const float depth = fminf(fmaxf(1.0f / sig - 1.0f, 0.1f), 200.0f);

    const float fu = calib[0], cu = calib[2], fv = calib[5], cv = calib[6];
    const float bxo = calib[3] / -fu;
    const float byo = calib[7] / -fv;
    const float locx = (cx * 4.0f - cu) * depth / fu + bxo;
    const float locy = (cy * 4.0f - cv) * depth / fv + byo;

    float best = -INFINITY;
    int bidx = 0;
#pragma unroll
    for (int t = 0; t < 4; ++t) {
        const float l0 = s[9 + 2 * t], l1 = s[9 + 2 * t + 1];
        const float mm = fmaxf(l0, l1);
        const float p1 = expf(l1 - mm) / (expf(l0 - mm) + expf(l1 - mm));
        if (p1 > best) { best = p1; bidx = t; }
    }
    const float sel0 = s[17 + 2 * bidx], sel1 = s[17 + 2 * bidx + 1];
    float alpha = atanf(sel0 / sel1) + ACENT[bidx];
    const float ray = atanf(locx / depth);
    float roty = alpha + ray;
    if (roty > PI_F) roty -= TWO_PI_F;
    if (roty < -PI_F) roty += TWO_PI_F;
    if (alpha > PI_F) alpha -= TWO_PI_F;
    if (alpha < -PI_F) alpha += TWO_PI_F;

    float* o = out + (size_t)i * 14;
    o[0] = bx1; o[1] = by1; o[2] = bx2; o[3] = by2;
    o[4] = dim0; o[5] = dim1; o[6] = dim2;
    o[7] = depth;
    o[8] = locx; o[9] = locy; o[10] = depth;
    o[11] = roty; o[12] = alpha;
    o[13] = score;
    out[NDET * 14 + i] = valid ? 1.0f : 0.0f;
    out[NDET * 15 + i] = (float)cls;
}

extern "C" void kernel_launch(void* const* d_in, const int* in_sizes, int n_in,
                              void* d_out, int out_size, void* d_ws, size_t ws_size,
                              hipStream_t stream) {
    const float* cls = (const float*)d_in[0];
    const float* regs = (const float*)d_in[1];
    const float* calib = (const float*)d_in[2];
    float* out = (float*)d_out;
    char* ws = (char*)d_ws;

    // ws layout (all regions rewritten each launch before being read)
    int* slabCnt = (int*)ws;                                         // 144*12*4 = 6912 B (pad 32K)
    unsigned long long* slabs = (unsigned long long*)(ws + 32768);   // 144*12*1024*8 = 14,155,776 B
    char* tail = ws + 32768 + 14155776;
    unsigned long long* planeKeys = (unsigned long long*)tail;       // 144*50*8 = 57,600 B
    float* dScore = (float*)(tail + 57600);                          // 800*4
    int* dInd = (int*)(tail + 60800);                                // 800*4
    int* dCls = (int*)(tail + 64000);                                // 800*4
    int* batchCnt = (int*)(tail + 67200);                            // 16*4

    hipLaunchKernelGGL(nms_wave, dim3(NCH, NPLANE), dim3(64), 0, stream, cls, slabs, slabCnt, batchCnt);
    hipLaunchKernelGGL(plane_topk, dim3(NPLANE), dim3(256), 0, stream, slabs, slabCnt, planeKeys,
                       batchCnt, dScore, dInd, dCls);
    hipLaunchKernelGGL(finalize, dim3(NDET), dim3(64), 0, stream, regs, calib, dScore, dInd, dCls, out);
}

// Round 10
// 61.498 us; speedup vs baseline: 1.4776x; 1.4776x over previous
//
#include <hip/hip_runtime.h>
#include <math.h>

#define Hd 264
#define Wd 480
#define HW (Hd * Wd)
#define NB 16
#define NC 9
#define KK 50
#define NPLANE (NB * NC)
#define NDET (NB * KK)
#define CAP 6912
#define K1CH 8                     // chunks per plane in K1
#define F4PC (HW / 4 / K1CH)       // 3960 float4 per chunk
#define SLAB_CAP 512               // expected ~32 hits/chunk; >10 sigma margin
#define SCAP 1024
#define TB_F 0.998f
#define PI_F 3.14159274101257324f
#define TWO_PI_F 6.28318548202514648f

__device__ const float DIMM[9][3] = {
    {3.99331126f, 1.54370861f, 1.64175497f},
    {0.295f, 1.6f, 0.3175f},
    {1.34645161f, 1.55322581f, 0.3883871f},
    {2.503f, 1.72f, 1.077f},
    {9.1775f, 2.95f, 2.3425f},
    {10.3655102f, 3.31632653f, 2.45469388f},
    {6.016911083f, 3.412001685f, 2.2783185f},
    {4.824963f, 2.046904f, 1.78939f},
    {8.8040879f, 2.916193f, 2.07649252f}};

__device__ const float ACENT[4] = {0.0f, 1.57079637050628662f, 3.14159274101257324f, -1.57079637050628662f};

__device__ __forceinline__ unsigned long long mkkey(float v, unsigned int idx) {
    return ((unsigned long long)__float_as_uint(v) << 32) | (unsigned long long)(0xFFFFFFFFu - idx);
}

// Kernel 1: streaming threshold filter. Pixels with value >= TB_F appended to a
// private per-(plane,chunk) slab + RAW count (K2 detects overflow via count>cap).
// Near-zero VALU; HBM-bound. Also zeroes the fan-in batch counters (plain store,
// visible to K2 across the kernel boundary). Graph-replay safe (no pre-zeroing).
__global__ __launch_bounds__(256) void thresh_scan(const float* __restrict__ cls,
                                                   unsigned long long* __restrict__ slabs,
                                                   int* __restrict__ slabCnt,
                                                   int* __restrict__ batchCnt) {
    __shared__ unsigned long long sbuf[SLAB_CAP];
    __shared__ int scnt;

    const int plane = blockIdx.y;
    const int chunk = blockIdx.x;
    const int tid = threadIdx.x;
    if (tid == 0) {
        scnt = 0;
        if (chunk == 0 && plane < NB) batchCnt[plane] = 0;
    }
    __syncthreads();

    const float4* hp4 = (const float4*)(cls + (size_t)plane * HW) + (size_t)chunk * F4PC;
    const unsigned int base = (unsigned int)(chunk * F4PC * 4);

    for (int q = tid; q < F4PC; q += 256) {
        const float4 v = hp4[q];
        const unsigned int i0 = base + 4u * (unsigned int)q;
        if (v.x >= TB_F) { const int p = atomicAdd(&scnt, 1); if (p < SLAB_CAP) sbuf[p] = mkkey(v.x, i0); }
        if (v.y >= TB_F) { const int p = atomicAdd(&scnt, 1); if (p < SLAB_CAP) sbuf[p] = mkkey(v.y, i0 + 1); }
        if (v.z >= TB_F) { const int p = atomicAdd(&scnt, 1); if (p < SLAB_CAP) sbuf[p] = mkkey(v.z, i0 + 2); }
        if (v.w >= TB_F) { const int p = atomicAdd(&scnt, 1); if (p < SLAB_CAP) sbuf[p] = mkkey(v.w, i0 + 3); }
    }
    __syncthreads();
    const int n = min(scnt, SLAB_CAP);
    unsigned long long* dst = slabs + (size_t)(plane * K1CH + chunk) * SLAB_CAP;
    for (int j = tid; j < n; j += 256) dst[j] = sbuf[j];
    if (tid == 0) slabCnt[plane * K1CH + chunk] = scnt;  // raw (overflow-detectable)
}

// Kernel 2: one block per plane. Gather candidates (>=TB pixels), verify 5x5 NMS
// by direct window reads, rank survivors (prefix-closed set -> global ranks are
// exact). Fallback (overflow / <50 survivors): brute-force full-plane NMS +
// 50-round argmax (any-data correct). Then device-scope fan-in: last of each
// batch's 9 blocks ranks the batch's 450 keys.
__global__ __launch_bounds__(256) void select_topk(const float* __restrict__ cls,
                                                   const unsigned long long* __restrict__ slabs,
                                                   const int* __restrict__ slabCnt,
                                                   unsigned long long* __restrict__ planeKeys,
                                                   int* __restrict__ batchCnt,
                                                   float* __restrict__ dScore,
                                                   int* __restrict__ dInd,
                                                   int* __restrict__ dCls) {
    __shared__ unsigned long long candG[CAP];   // 55.3 KB (gather / fallback survivors)
    __shared__ unsigned long long S[SCAP];      // 8 KB
    __shared__ unsigned int sidx[NC * KK];      // 1.8 KB (fan-in)
    __shared__ int soff[K1CH + 1];
    __shared__ int s_scnt, s_over, s_last;
    __shared__ unsigned long long wmax_[4];
    __shared__ unsigned long long sprev;

    const int plane = blockIdx.x;
    const int tid = threadIdx.x;
    const float* hp = cls + (size_t)plane * HW;

    if (tid == 0) { s_scnt = 0; s_over = 0; }
    __syncthreads();
    if (tid < K1CH) {
        const int c = slabCnt[plane * K1CH + tid];
        soff[tid + 1] = min(c, SLAB_CAP);
        if (c > SLAB_CAP) atomicAdd(&s_over, 1);
    }
    __syncthreads();
    if (tid == 0) {
        soff[0] = 0;
        for (int c = 1; c <= K1CH; ++c) soff[c] += soff[c - 1];
    }
    __syncthreads();
    const int n = soff[K1CH];

    for (int j = tid; j < n; j += 256) {
        int lo = 0, hi = K1CH;
        while (hi - lo > 1) { const int mid = (lo + hi) >> 1; if (soff[mid] <= j) lo = mid; else hi = mid; }
        candG[j] = slabs[(size_t)(plane * K1CH + lo) * SLAB_CAP + (j - soff[lo])];
    }
    __syncthreads();

    // NMS-verify each candidate with a direct 25-point window read.
    for (int j = tid; j < n; j += 256) {
        const unsigned long long k = candG[j];
        const unsigned int idx = 0xFFFFFFFFu - (unsigned int)(k & 0xFFFFFFFFull);
        const float v = __uint_as_float((unsigned int)(k >> 32));
        const int y = (int)idx / Wd, x = (int)idx - ((int)idx / Wd) * Wd;
        const int ylo = max(y - 2, 0), yhi = min(y + 2, Hd - 1);
        const int xlo = max(x - 2, 0), xhi = min(x + 2, Wd - 1);
        float wm = -INFINITY;
        for (int yy = ylo; yy <= yhi; ++yy)
            for (int xx = xlo; xx <= xhi; ++xx)
                wm = fmaxf(wm, hp[yy * Wd + xx]);
        if (v == wm) {  // survivor (non-strict tie, matches hmax==heat)
            const int p = atomicAdd(&s_scnt, 1);
            if (p < SCAP) S[p] = k;
        }
    }
    __syncthreads();
    const int sc = s_scnt;

    if (s_over == 0 && sc >= KK && sc <= SCAP) {
        // Exact rank = count-greater within the prefix-closed survivor set.
        for (int idx = tid; idx < sc; idx += 256) {
            const unsigned long long k = S[idx];
            int r = 0;
            for (int j = 0; j < sc; ++j) r += (S[j] > k) ? 1 : 0;
            if (r < KK) planeKeys[plane * KK + r] = k;
        }
    } else {
        // Fallback: brute-force full-plane NMS into candG, then 50-round argmax.
        if (tid == 0) s_scnt = 0;
        for (int j = tid; j < KK; j += 256) planeKeys[plane * KK + j] = 0;
        __syncthreads();
        for (int px = tid; px < HW; px += 256) {
            const float v = hp[px];
            const int y = px / Wd, x = px - (px / Wd) * Wd;
            const int ylo = max(y - 2, 0), yhi = min(y + 2, Hd - 1);
            const int xlo = max(x - 2, 0), xhi = min(x + 2, Wd - 1);
            float wm = -INFINITY;
            for (int yy = ylo; yy <= yhi; ++yy)
                for (int xx = xlo; xx <= xhi; ++xx)
                    wm = fmaxf(wm, hp[yy * Wd + xx]);
            if (v == wm) {
                const int p = atomicAdd(&s_scnt, 1);
                if (p < CAP) candG[p] = mkkey(v, (unsigned int)px);
            }
        }
        __syncthreads();
        const int nn = min(s_scnt, CAP);
        unsigned long long prev = ~0ull;
        for (int it = 0; it < KK; ++it) {
            unsigned long long mk = 0;
            for (int j = tid; j < nn; j += 256) {
                unsigned long long k = candG[j];
                if (k == prev) { candG[j] = 0; k = 0; }
                if (k > mk) mk = k;
            }
            for (int s = 32; s > 0; s >>= 1) {
                const unsigned long long o = __shfl_down(mk, s);
                if (o > mk) mk = o;
            }
            if ((tid & 63) == 0) wmax_[tid >> 6] = mk;
            __syncthreads();
            if (tid == 0) {
                unsigned long long m = wmax_[0];
                if (wmax_[1] > m) m = wmax_[1];
                if (wmax_[2] > m) m = wmax_[2];
                if (wmax_[3] > m) m = wmax_[3];
                planeKeys[plane * KK + it] = m;
                sprev = m;
            }
            __syncthreads();
            prev = sprev;
        }
    }

    // Fan-in: last finishing block of each batch ranks the batch's 450 keys.
    __threadfence();
    __syncthreads();
    if (tid == 0) s_last = (atomicAdd(&batchCnt[plane / NC], 1) == NC - 1) ? 1 : 0;
    __syncthreads();
    if (!s_last) return;
    __threadfence();

    const int b = plane / NC;
    for (int j = tid; j < NC * KK; j += 256) {
        const unsigned long long pk = planeKeys[(b * NC + j / KK) * KK + (j % KK)];
        sidx[j] = 0xFFFFFFFFu - (unsigned int)(pk & 0xFFFFFFFFull);
        S[j] = (pk & 0xFFFFFFFF00000000ull) | (unsigned long long)(0xFFFFFFFFu - (unsigned int)j);
    }
    __syncthreads();
    for (int idx = tid; idx < NC * KK; idx += 256) {
        const unsigned long long k = S[idx];
        int r = 0;
        for (int j = 0; j < NC * KK; ++j) r += (S[j] > k) ? 1 : 0;
        if (r < KK) {
            dScore[b * KK + r] = __uint_as_float((unsigned int)(k >> 32));
            dInd[b * KK + r] = (int)sidx[idx];
            dCls[b * KK + r] = idx / KK;
        }
    }
}

// Kernel 3 (unchanged): fused per-detection finalize, 800 blocks x 64.
__global__ __launch_bounds__(64) void finalize(const float* __restrict__ regs,
                                               const float* __restrict__ calib,
                                               const float* __restrict__ dScore,
                                               const int* __restrict__ dInd,
                                               const int* __restrict__ dCls,
                                               float* __restrict__ out) {
    __shared__ float s[26];
    const int i = blockIdx.x;
    const int lane = threadIdx.x;
    const int ind0 = dInd[i];
    const int ind = (ind0 >= 0 && ind0 < HW) ? ind0 : 0;
    const int b = i / KK;

    if (lane < 26) {
        const int ch = (lane < 6) ? lane : lane + 16;  // 0-5, 22-24, 25-40, 41
        s[lane] = regs[(size_t)b * 46 * HW + (size_t)ch * HW + (size_t)ind];
    }

    float m = -INFINITY;
    for (int j = lane; j < NDET; j += 64) {
        if (dInd[j] == ind0 && dScore[j] >= 0.29f) {
            m = fmaxf(m, (float)dCls[j] * 10000.0f - (float)j);
        }
    }
#pragma unroll
    for (int sft = 32; sft > 0; sft >>= 1) m = fmaxf(m, __shfl_down(m, sft));
    __syncthreads();
    if (lane != 0) return;

    const int cls = dCls[i];
    const float score = dScore[i];
    const bool th = score >= 0.29f;
    const float key_i = th ? (float)cls * 10000.0f - (float)i : -INFINITY;
    const bool valid = th && (key_i == m);

    const float x = (float)(ind % Wd);
    const float y = (float)(ind / Wd);

    const float r0 = fmaxf(s[0], 0.0f), r1 = fmaxf(s[1], 0.0f);
    const float r2 = fmaxf(s[2], 0.0f), r3 = fmaxf(s[3], 0.0f);
    const float cx = x + s[4];
    const float cy = y + s[5];

    const float bx1 = fminf(fmaxf((cx - r0) * 4.0f, 0.0f), 1920.0f);
    const float by1 = fminf(fmaxf((cy - r1) * 4.0f, 0.0f), 1056.0f);
    const float bx2 = fminf(fmaxf((cx + r2) * 4.0f, 0.0f), 1920.0f);
    const float by2 = fminf(fmaxf((cy + r3) * 4.0f, 0.0f), 1056.0f);

    const float dim0 = expf(s[6]) * DIMM[cls][0];
    const float dim1 = expf(s[7]) * DIMM[cls][1];
    const float dim2 = expf(s[8]) * DIMM[cls][2];

    const float sig = 1.0f / (1.0f + expf(-s[25]));
    const float depth = fminf(fmaxf(1.0f / sig - 1.0f, 0.1f), 200.0f);

    const float fu = calib[0], cu = calib[2], fv = calib[5], cv = calib[6];
    const float bxo = calib[3] / -fu;
    const float byo = calib[7] / -fv;
    const float locx = (cx * 4.0f - cu) * depth / fu + bxo;
    const float locy = (cy * 4.0f - cv) * depth / fv + byo;

    float best = -INFINITY;
    int bidx = 0;
#pragma unroll
    for (int t = 0; t < 4; ++t) {
        const float l0 = s[9 + 2 * t], l1 = s[9 + 2 * t + 1];
        const float mm = fmaxf(l0, l1);
        const float p1 = expf(l1 - mm) / (expf(l0 - mm) + expf(l1 - mm));
        if (p1 > best) { best = p1; bidx = t; }
    }
    const float sel0 = s[17 + 2 * bidx], sel1 = s[17 + 2 * bidx + 1];
    float alpha = atanf(sel0 / sel1) + ACENT[bidx];
    const float ray = atanf(locx / depth);
    float roty = alpha + ray;
    if (roty > PI_F) roty -= TWO_PI_F;
    if (roty < -PI_F) roty += TWO_PI_F;
    if (alpha > PI_F) alpha -= TWO_PI_F;
    if (alpha < -PI_F) alpha += TWO_PI_F;

    float* o = out + (size_t)i * 14;
    o[0] = bx1; o[1] = by1; o[2] = bx2; o[3] = by2;
    o[4] = dim0; o[5] = dim1; o[6] = dim2;
    o[7] = depth;
    o[8] = locx; o[9] = locy; o[10] = depth;
    o[11] = roty; o[12] = alpha;
    o[13] = score;
    out[NDET * 14 + i] = valid ? 1.0f : 0.0f;
    out[NDET * 15 + i] = (float)cls;
}

extern "C" void kernel_launch(void* const* d_in, const int* in_sizes, int n_in,
                              void* d_out, int out_size, void* d_ws, size_t ws_size,
                              hipStream_t stream) {
    const float* cls = (const float*)d_in[0];
    const float* regs = (const float*)d_in[1];
    const float* calib = (const float*)d_in[2];
    float* out = (float*)d_out;
    char* ws = (char*)d_ws;

    // ws layout (all regions rewritten each launch before being read)
    int* slabCnt = (int*)ws;                                         // 144*8*4 = 4608 B (pad 32K)
    unsigned long long* slabs = (unsigned long long*)(ws + 32768);   // 144*8*512*8 = 4,718,592 B
    char* tail = ws + 32768 + 4718592;
    unsigned long long* planeKeys = (unsigned long long*)tail;       // 144*50*8 = 57,600 B
    float* dScore = (float*)(tail + 57600);                          // 800*4
    int* dInd = (int*)(tail + 60800);                                // 800*4
    int* dCls = (int*)(tail + 64000);                                // 800*4
    int* batchCnt = (int*)(tail + 67200);                            // 16*4

    hipLaunchKernelGGL(thresh_scan, dim3(K1CH, NPLANE), dim3(256), 0, stream, cls, slabs, slabCnt, batchCnt);
    hipLaunchKernelGGL(select_topk, dim3(NPLANE), dim3(256), 0, stream, cls, slabs, slabCnt,
                       planeKeys, batchCnt, dScore, dInd, dCls);
    hipLaunchKernelGGL(finalize, dim3(NDET), dim3(64), 0, stream, regs, calib, dScore, dInd, dCls, out);
}